// Round 3
// baseline (240.883 us; speedup 1.0000x reference)
//
#include <hip/hip_runtime.h>
#include <hip/hip_bf16.h>

#define N_   4096
#define CIN  256
#define CH_  256
#define NH_  8
#define DH_  32

typedef __attribute__((ext_vector_type(8))) short bf16x8;
typedef __attribute__((ext_vector_type(4))) float f32x4;

static __device__ inline unsigned short f2bf(float f) {
    union { float f; unsigned u; } x; x.f = f;
    unsigned r = x.u + 0x7FFFu + ((x.u >> 16) & 1u);
    return (unsigned short)(r >> 16);
}

// ---------------- 1) weight norm: W[mat][ch][c] = g[ch]*v[ch][c]/||v[ch,:]|| (bf16) ----
__global__ void wn_kernel(const float* __restrict__ vq, const float* __restrict__ gq,
                          const float* __restrict__ vk, const float* __restrict__ gk,
                          const float* __restrict__ vv, const float* __restrict__ gv,
                          unsigned short* __restrict__ W)
{
    int row = blockIdx.x & 255;
    int mat = blockIdx.x >> 8;
    const float* v = (mat == 0) ? vq : (mat == 1 ? vk : vv);
    const float* g = (mat == 0) ? gq : (mat == 1 ? gk : gv);
    int lane = threadIdx.x;  // 64 threads
    float4 x = *(const float4*)(v + (size_t)row * CIN + lane * 4);
    float ss = x.x*x.x + x.y*x.y + x.z*x.z + x.w*x.w;
    for (int m = 1; m < 64; m <<= 1) ss += __shfl_xor(ss, m);
    float sc = g[row] * rsqrtf(ss);
    unsigned short w4[4] = {f2bf(x.x*sc), f2bf(x.y*sc), f2bf(x.z*sc), f2bf(x.w*sc)};
    *(unsigned long long*)(W + (size_t)mat*65536 + (size_t)row*CIN + lane*4) =
        *(unsigned long long*)w4;
}

// ---------------- 2) projection GEMMs: out[n][ch] = X^T W^T + b --------------------
// X is [C][N] fp32 (channel-major). Q,K stored [head][n][32] bf16; V stored [head][32][n].
__global__ __launch_bounds__(256) void proj_kernel(
    const float* __restrict__ query, const float* __restrict__ keyf,
    const unsigned short* __restrict__ W,
    const float* __restrict__ bq, const float* __restrict__ bk, const float* __restrict__ bv,
    unsigned short* __restrict__ Qb, unsigned short* __restrict__ Kb,
    unsigned short* __restrict__ VTb)
{
    int wave = threadIdx.x >> 6;
    int lane = threadIdx.x & 63;
    int task = blockIdx.x * 4 + wave;   // 0..767
    int mat   = task >> 8;              // 0=q,1=k,2=v
    int ntile = task & 255;
    int nbase = ntile * 16;
    const float* X = (mat == 0) ? query : keyf;
    const unsigned short* Wm = W + (size_t)mat * 65536;
    const float* bias = (mat == 0) ? bq : (mat == 1 ? bk : bv);
    float scale = (mat == 0) ? 0.17677669529663687f : 1.0f;  // 1/sqrt(32) folded into Q

    int lg = lane >> 4;   // 0..3
    int lr = lane & 15;   // 0..15

    f32x4 acc[16];
    #pragma unroll
    for (int t = 0; t < 16; ++t) acc[t] = (f32x4){0,0,0,0};

    for (int kk = 0; kk < 8; ++kk) {
        int c0 = kk*32 + lg*8;
        bf16x8 a;
        #pragma unroll
        for (int j = 0; j < 8; ++j)
            ((unsigned short*)&a)[j] = f2bf(X[(size_t)(c0 + j) * N_ + nbase + lr]);
        #pragma unroll
        for (int t = 0; t < 16; ++t) {
            bf16x8 b = *(const bf16x8*)(Wm + (size_t)(t*16 + lr)*CIN + c0);
            acc[t] = __builtin_amdgcn_mfma_f32_16x16x32_bf16(a, b, acc[t], 0, 0, 0);
        }
    }
    #pragma unroll
    for (int t = 0; t < 16; ++t) {
        int ch = t*16 + lr;
        float bb = bias[ch];
        int head = ch >> 5, d = ch & 31;
        #pragma unroll
        for (int r = 0; r < 4; ++r) {
            int n = nbase + lg*4 + r;
            unsigned short val = f2bf((acc[t][r] + bb) * scale);
            if (mat == 0)      Qb[((size_t)head*N_ + n)*DH_ + d] = val;
            else if (mat == 1) Kb[((size_t)head*N_ + n)*DH_ + d] = val;
            else               VTb[((size_t)head*DH_ + d)*N_ + n] = val;
        }
    }
}

// ---------------- 3) strict-causal flash attention ---------------------------------
// 1 wave per block; wave handles 16 query rows of one head. 32 keys/iter.
__global__ __launch_bounds__(64) void attn_kernel(
    const unsigned short* __restrict__ Qb, const unsigned short* __restrict__ Kb,
    const unsigned short* __restrict__ VTb, float* __restrict__ out)
{
    __shared__ __attribute__((aligned(16))) unsigned short p_lds[16][40]; // +8 pad: no bank conflict
    int lane = threadIdx.x;
    int task = blockIdx.x;            // 0..2047
    int head = task & 7;
    int qtile = 255 - (task >> 3);    // largest trip count launched first
    int qbase = qtile * 16;
    int lg = lane >> 4, lr = lane & 15;

    const unsigned short* Qh = Qb  + (size_t)head * N_ * DH_;
    const unsigned short* Kh = Kb  + (size_t)head * N_ * DH_;
    const unsigned short* Vh = VTb + (size_t)head * DH_ * N_;

    bf16x8 qf = *(const bf16x8*)(Qh + (size_t)(qbase + lr) * DH_ + lg * 8);

    f32x4 o0 = {0,0,0,0}, o1 = {0,0,0,0};
    f32x4 zero = {0,0,0,0};
    float m[4]   = {-1e30f,-1e30f,-1e30f,-1e30f};
    float sum[4] = {0,0,0,0};

    int kmax = qbase + 15;  // keys needed: j < row <= qbase+15
    for (int kb = 0; kb < kmax; kb += 32) {
        bf16x8 k0 = *(const bf16x8*)(Kh + (size_t)(kb      + lr) * DH_ + lg * 8);
        bf16x8 k1 = *(const bf16x8*)(Kh + (size_t)(kb + 16 + lr) * DH_ + lg * 8);
        f32x4 s0 = __builtin_amdgcn_mfma_f32_16x16x32_bf16(qf, k0, zero, 0,0,0);
        f32x4 s1 = __builtin_amdgcn_mfma_f32_16x16x32_bf16(qf, k1, zero, 0,0,0);

        if (kb + 31 >= qbase) {      // diagonal region: strict-causal mask
            #pragma unroll
            for (int r = 0; r < 4; ++r) {
                int row = qbase + lg*4 + r;
                if (kb + lr      >= row) s0[r] = -INFINITY;
                if (kb + 16 + lr >= row) s1[r] = -INFINITY;
            }
        }
        #pragma unroll
        for (int r = 0; r < 4; ++r) {
            float v = fmaxf(s0[r], s1[r]);
            v = fmaxf(v, __shfl_xor(v, 1));
            v = fmaxf(v, __shfl_xor(v, 2));
            v = fmaxf(v, __shfl_xor(v, 4));
            v = fmaxf(v, __shfl_xor(v, 8));
            float mnew = fmaxf(m[r], v);
            float fac  = __expf(m[r] - mnew);
            float p0   = __expf(s0[r] - mnew);
            float p1   = __expf(s1[r] - mnew);
            float rs = p0 + p1;
            rs += __shfl_xor(rs, 1); rs += __shfl_xor(rs, 2);
            rs += __shfl_xor(rs, 4); rs += __shfl_xor(rs, 8);
            sum[r] = sum[r] * fac + rs;
            o0[r] *= fac;  o1[r] *= fac;
            m[r] = mnew;
            p_lds[lg*4 + r][lr]      = f2bf(p0);
            p_lds[lg*4 + r][16 + lr] = f2bf(p1);
        }
        __syncthreads();   // single-wave block: cheap; makes all lanes' P writes visible
        bf16x8 pa = *(const bf16x8*)(&p_lds[lr][lg*8]);
        bf16x8 v0 = *(const bf16x8*)(Vh + (size_t)lr        * N_ + kb + lg*8);
        bf16x8 v1 = *(const bf16x8*)(Vh + (size_t)(16 + lr) * N_ + kb + lg*8);
        o0 = __builtin_amdgcn_mfma_f32_16x16x32_bf16(pa, v0, o0, 0,0,0);
        o1 = __builtin_amdgcn_mfma_f32_16x16x32_bf16(pa, v1, o1, 0,0,0);
        __syncthreads();   // keep P reads ordered before next iteration's writes
    }

    #pragma unroll
    for (int r = 0; r < 4; ++r) {
        int row = qbase + lg*4 + r;
        float inv = (row == 0) ? 0.0f : 1.0f / sum[r];
        out[(size_t)(head*DH_ + lr)      * N_ + row] = o0[r] * inv;
        out[(size_t)(head*DH_ + 16 + lr) * N_ + row] = o1[r] * inv;
    }
}

extern "C" void kernel_launch(void* const* d_in, const int* in_sizes, int n_in,
                              void* d_out, int out_size, void* d_ws, size_t ws_size,
                              hipStream_t stream) {
    const float* query = (const float*)d_in[0];
    const float* keyf  = (const float*)d_in[1];
    const float* vq = (const float*)d_in[2];
    const float* gq = (const float*)d_in[3];
    const float* bq = (const float*)d_in[4];
    const float* vk = (const float*)d_in[5];
    const float* gk = (const float*)d_in[6];
    const float* bk = (const float*)d_in[7];
    const float* vv = (const float*)d_in[8];
    const float* gv = (const float*)d_in[9];
    const float* bv = (const float*)d_in[10];

    char* ws = (char*)d_ws;
    unsigned short* W   = (unsigned short*)ws;                         // 3*256*256*2 = 384 KB
    unsigned short* Qb  = (unsigned short*)(ws + 393216);              // 2 MB
    unsigned short* Kb  = (unsigned short*)(ws + 393216 + 2097152);    // 2 MB
    unsigned short* VTb = (unsigned short*)(ws + 393216 + 2*2097152);  // 2 MB
    float* out = (float*)d_out;

    hipLaunchKernelGGL(wn_kernel,   dim3(768),  dim3(64),  0, stream,
                       vq, gq, vk, gk, vv, gv, W);
    hipLaunchKernelGGL(proj_kernel, dim3(192),  dim3(256), 0, stream,
                       query, keyf, W, bq, bk, bv, Qb, Kb, VTb);
    hipLaunchKernelGGL(attn_kernel, dim3(2048), dim3(64),  0, stream,
                       Qb, Kb, VTb, out);
}

// Round 4
// 201.422 us; speedup vs baseline: 1.1959x; 1.1959x over previous
//
#include <hip/hip_runtime.h>
#include <hip/hip_bf16.h>

#define N_    4096
#define CIN   256
#define NH_   8
#define DH_   32
#define CHUNK 1024
#define KVB   64

typedef __attribute__((ext_vector_type(8))) short bf16x8;
typedef __attribute__((ext_vector_type(4))) float f32x4;

static __device__ inline unsigned short f2bf(float f) {
    union { float f; unsigned u; } x; x.f = f;
    unsigned r = x.u + 0x7FFFu + ((x.u >> 16) & 1u);
    return (unsigned short)(r >> 16);
}
static __device__ inline float bf2f(unsigned short s) {
    union { unsigned u; float f; } x; x.u = ((unsigned)s) << 16;
    return x.f;
}

// ---------------- 1) weight norm: W[mat][ch][c] = g[ch]*v[ch][c]/||v[ch,:]|| (bf16) ----
__global__ void wn_kernel(const float* __restrict__ vq, const float* __restrict__ gq,
                          const float* __restrict__ vk, const float* __restrict__ gk,
                          const float* __restrict__ vv, const float* __restrict__ gv,
                          unsigned short* __restrict__ W)
{
    int row = blockIdx.x & 255;
    int mat = blockIdx.x >> 8;
    const float* v = (mat == 0) ? vq : (mat == 1 ? vk : vv);
    const float* g = (mat == 0) ? gq : (mat == 1 ? gk : gv);
    int lane = threadIdx.x;  // 64 threads
    float4 x = *(const float4*)(v + (size_t)row * CIN + lane * 4);
    float ss = x.x*x.x + x.y*x.y + x.z*x.z + x.w*x.w;
    for (int m = 1; m < 64; m <<= 1) ss += __shfl_xor(ss, m);
    float sc = g[row] * rsqrtf(ss);
    unsigned short w4[4] = {f2bf(x.x*sc), f2bf(x.y*sc), f2bf(x.z*sc), f2bf(x.w*sc)};
    *(unsigned long long*)(W + (size_t)mat*65536 + (size_t)row*CIN + lane*4) =
        *(unsigned long long*)w4;
}

// ---------------- 2) projection GEMMs ------------------------------------------------
// Block = one (mat, 16-row n-tile). 4 waves; A-tile staged once in LDS (bf16, transposed),
// each wave computes 64 output channels. Q scale folds 1/sqrt(32)*log2(e) for exp2 softmax.
__global__ __launch_bounds__(256) void proj_kernel(
    const float* __restrict__ query, const float* __restrict__ keyf,
    const unsigned short* __restrict__ W,
    const float* __restrict__ bq, const float* __restrict__ bk, const float* __restrict__ bv,
    unsigned short* __restrict__ Qb, unsigned short* __restrict__ Kb,
    unsigned short* __restrict__ VTb)
{
    __shared__ unsigned short At[16][272];   // [n][c], stride 272 to spread banks
    int t = threadIdx.x;
    int mat   = blockIdx.x >> 8;            // 0=q,1=k,2=v
    int ntile = blockIdx.x & 255;
    int nbase = ntile * 16;
    const float* X = (mat == 0) ? query : keyf;
    const unsigned short* Wm = W + (size_t)mat * 65536;
    const float* bias = (mat == 0) ? bq : (mat == 1 ? bk : bv);
    float scale = (mat == 0) ? 0.2550695314903135f : 1.0f;  // log2(e)/sqrt(32) folded into Q

    int tr = t >> 4;   // c sub-index
    int tn = t & 15;   // n
    #pragma unroll
    for (int p = 0; p < 16; ++p) {
        int c = p*16 + tr;
        At[tn][c] = f2bf(X[(size_t)c * N_ + nbase + tn]);
    }
    __syncthreads();

    int w = t >> 6;
    int lane = t & 63;
    int lg = lane >> 4;   // 0..3
    int lr = lane & 15;   // 0..15

    f32x4 acc[4];
    #pragma unroll
    for (int tt = 0; tt < 4; ++tt) acc[tt] = (f32x4){0,0,0,0};

    #pragma unroll
    for (int kk = 0; kk < 8; ++kk) {
        int c0 = kk*32 + lg*8;
        bf16x8 a = *(const bf16x8*)&At[lr][c0];
        #pragma unroll
        for (int tt = 0; tt < 4; ++tt) {
            int ch = w*64 + tt*16 + lr;
            bf16x8 b = *(const bf16x8*)(Wm + (size_t)ch*CIN + c0);
            acc[tt] = __builtin_amdgcn_mfma_f32_16x16x32_bf16(a, b, acc[tt], 0, 0, 0);
        }
    }
    #pragma unroll
    for (int tt = 0; tt < 4; ++tt) {
        int ch = w*64 + tt*16 + lr;
        float bb = bias[ch];
        int head = ch >> 5, d = ch & 31;
        #pragma unroll
        for (int r = 0; r < 4; ++r) {
            int n = nbase + lg*4 + r;
            unsigned short val = f2bf((acc[tt][r] + bb) * scale);
            if (mat == 0)      Qb[((size_t)head*N_ + n)*DH_ + d] = val;
            else if (mat == 1) Kb[((size_t)head*N_ + n)*DH_ + d] = val;
            else               VTb[((size_t)head*DH_ + d)*N_ + n] = val;
        }
    }
}

// ---------------- 3) split-K flash attention (partials) ------------------------------
// Grid: head(8) x qtile(256) x chunk(4). 1 wave/block, 16 q-rows, 64 keys/iter.
// exp2-domain softmax (scale folded into Q), defer-max THR=8.
__global__ __launch_bounds__(64) void attn_kernel(
    const unsigned short* __restrict__ Qb, const unsigned short* __restrict__ Kb,
    const unsigned short* __restrict__ VTb,
    float* __restrict__ Pm, float* __restrict__ Ps, unsigned short* __restrict__ Po)
{
    __shared__ __attribute__((aligned(16))) unsigned short p_lds[16][72];
    int lane = threadIdx.x;
    int b = blockIdx.x;
    int chunk = b & 3;
    int qtile = (b >> 2) & 255;
    int head  = b >> 10;
    int qbase = qtile * 16;
    int kmax  = qbase + 15;            // keys j satisfy j < row <= qbase+15
    int kstart = chunk * CHUNK;
    int idx = ((head << 8) + qtile) * 4 + chunk;

    if (kstart >= kmax) {              // empty chunk: mark sums zero for combine
        if (lane < 16) Ps[(size_t)idx*16 + lane] = 0.0f;
        return;
    }
    int kend = min(kmax, kstart + CHUNK);
    int lg = lane >> 4, lr = lane & 15;

    const unsigned short* Qh = Qb  + (size_t)head * N_ * DH_;
    const unsigned short* Kh = Kb  + (size_t)head * N_ * DH_;
    const unsigned short* Vh = VTb + (size_t)head * DH_ * N_;

    bf16x8 qf = *(const bf16x8*)(Qh + (size_t)(qbase + lr) * DH_ + lg * 8);

    f32x4 o0 = {0,0,0,0}, o1 = {0,0,0,0};
    f32x4 zero = {0,0,0,0};
    float m[4]   = {-1e30f,-1e30f,-1e30f,-1e30f};
    float sum[4] = {0,0,0,0};

    for (int kb = kstart; kb < kend; kb += KVB) {
        f32x4 s[4];
        #pragma unroll
        for (int j = 0; j < 4; ++j) {
            bf16x8 kf = *(const bf16x8*)(Kh + (size_t)(kb + j*16 + lr) * DH_ + lg * 8);
            s[j] = __builtin_amdgcn_mfma_f32_16x16x32_bf16(qf, kf, zero, 0, 0, 0);
        }
        if (kb + KVB - 1 >= qbase) {   // diagonal region: strict-causal mask
            #pragma unroll
            for (int j = 0; j < 4; ++j)
                #pragma unroll
                for (int r = 0; r < 4; ++r)
                    if (kb + j*16 + lr >= qbase + lg*4 + r) s[j][r] = -INFINITY;
        }
        #pragma unroll
        for (int r = 0; r < 4; ++r) {
            float v = fmaxf(fmaxf(s[0][r], s[1][r]), fmaxf(s[2][r], s[3][r]));
            v = fmaxf(v, __shfl_xor(v, 1));
            v = fmaxf(v, __shfl_xor(v, 2));
            v = fmaxf(v, __shfl_xor(v, 4));
            v = fmaxf(v, __shfl_xor(v, 8));
            if (v > m[r] + 8.0f) {     // defer-max: rescale only on real growth
                float fac = exp2f(m[r] - v);
                o0[r] *= fac; o1[r] *= fac; sum[r] *= fac;
                m[r] = v;
            }
            float p0 = exp2f(s[0][r] - m[r]);
            float p1 = exp2f(s[1][r] - m[r]);
            float p2 = exp2f(s[2][r] - m[r]);
            float p3 = exp2f(s[3][r] - m[r]);
            float rs = (p0 + p1) + (p2 + p3);
            rs += __shfl_xor(rs, 1); rs += __shfl_xor(rs, 2);
            rs += __shfl_xor(rs, 4); rs += __shfl_xor(rs, 8);
            sum[r] += rs;
            int row = lg*4 + r;
            p_lds[row][lr]      = f2bf(p0);
            p_lds[row][16 + lr] = f2bf(p1);
            p_lds[row][32 + lr] = f2bf(p2);
            p_lds[row][48 + lr] = f2bf(p3);
        }
        __syncthreads();
        #pragma unroll
        for (int ks = 0; ks < 2; ++ks) {
            bf16x8 pa = *(const bf16x8*)&p_lds[lr][ks*32 + lg*8];
            bf16x8 v0 = *(const bf16x8*)(Vh + (size_t)lr        * N_ + kb + ks*32 + lg*8);
            bf16x8 v1 = *(const bf16x8*)(Vh + (size_t)(16 + lr) * N_ + kb + ks*32 + lg*8);
            o0 = __builtin_amdgcn_mfma_f32_16x16x32_bf16(pa, v0, o0, 0, 0, 0);
            o1 = __builtin_amdgcn_mfma_f32_16x16x32_bf16(pa, v1, o1, 0, 0, 0);
        }
        __syncthreads();
    }

    if (lr == 0) {
        #pragma unroll
        for (int r = 0; r < 4; ++r) {
            Pm[(size_t)idx*16 + lg*4 + r] = m[r];
            Ps[(size_t)idx*16 + lg*4 + r] = sum[r];
        }
    }
    unsigned short* Pob = Po + (size_t)idx * 512;   // [16 rows][32 d]
    #pragma unroll
    for (int r = 0; r < 4; ++r) {
        int row = lg*4 + r;
        Pob[row*32 + lr]      = f2bf(o0[r]);
        Pob[row*32 + 16 + lr] = f2bf(o1[r]);
    }
}

// ---------------- 4) combine partials across chunks ----------------------------------
__global__ __launch_bounds__(64) void combine_kernel(
    const float* __restrict__ Pm, const float* __restrict__ Ps,
    const unsigned short* __restrict__ Po, float* __restrict__ out)
{
    int b = blockIdx.x;            // head(8) x qtile(256)
    int qtile = b & 255;
    int head  = b >> 8;
    int lane = threadIdx.x;
    int row = lane & 15;
    int dg  = lane >> 4;           // d = dg*8 .. dg*8+7
    int base = ((head << 8) + qtile) * 4;

    float sc[4], mc[4];
    #pragma unroll
    for (int c = 0; c < 4; ++c) {
        sc[c] = Ps[(size_t)(base + c)*16 + row];
        mc[c] = (sc[c] > 0.0f) ? Pm[(size_t)(base + c)*16 + row] : -1e30f;
    }
    float M = fmaxf(fmaxf(mc[0], mc[1]), fmaxf(mc[2], mc[3]));
    float denom = 0.0f, wgt[4];
    #pragma unroll
    for (int c = 0; c < 4; ++c) {
        wgt[c] = (sc[c] > 0.0f) ? exp2f(mc[c] - M) : 0.0f;
        denom += sc[c] * wgt[c];
    }
    float acc[8] = {0,0,0,0,0,0,0,0};
    #pragma unroll
    for (int c = 0; c < 4; ++c) {
        if (wgt[c] != 0.0f) {
            const unsigned short* p = Po + (size_t)(base + c)*512 + row*32 + dg*8;
            #pragma unroll
            for (int i = 0; i < 8; ++i) acc[i] += wgt[c] * bf2f(p[i]);
        }
    }
    int grow = qtile*16 + row;
    float inv = (denom > 0.0f && grow != 0) ? 1.0f / denom : 0.0f;  // row 0: start_mask
    #pragma unroll
    for (int i = 0; i < 8; ++i)
        out[(size_t)(head*DH_ + dg*8 + i) * N_ + grow] = acc[i] * inv;
}

extern "C" void kernel_launch(void* const* d_in, const int* in_sizes, int n_in,
                              void* d_out, int out_size, void* d_ws, size_t ws_size,
                              hipStream_t stream) {
    const float* query = (const float*)d_in[0];
    const float* keyf  = (const float*)d_in[1];
    const float* vq = (const float*)d_in[2];
    const float* gq = (const float*)d_in[3];
    const float* bq = (const float*)d_in[4];
    const float* vk = (const float*)d_in[5];
    const float* gk = (const float*)d_in[6];
    const float* bk = (const float*)d_in[7];
    const float* vv = (const float*)d_in[8];
    const float* gv = (const float*)d_in[9];
    const float* bv = (const float*)d_in[10];

    char* ws = (char*)d_ws;
    unsigned short* W   = (unsigned short*)ws;                    // 384 KB
    unsigned short* Qb  = (unsigned short*)(ws + 393216);         // 2 MB
    unsigned short* Kb  = (unsigned short*)(ws + 2490368);        // 2 MB
    unsigned short* VTb = (unsigned short*)(ws + 4587520);        // 2 MB
    float*          Pm  = (float*)         (ws + 6684672);        // 512 KB
    float*          Ps  = (float*)         (ws + 7208960);        // 512 KB
    unsigned short* Po  = (unsigned short*)(ws + 7733248);        // 8 MB  (total 15.4 MB)
    float* out = (float*)d_out;

    hipLaunchKernelGGL(wn_kernel,      dim3(768),  dim3(64),  0, stream,
                       vq, gq, vk, gk, vv, gv, W);
    hipLaunchKernelGGL(proj_kernel,    dim3(768),  dim3(256), 0, stream,
                       query, keyf, W, bq, bk, bv, Qb, Kb, VTb);
    hipLaunchKernelGGL(attn_kernel,    dim3(8192), dim3(64),  0, stream,
                       Qb, Kb, VTb, Pm, Ps, Po);
    hipLaunchKernelGGL(combine_kernel, dim3(2048), dim3(64),  0, stream,
                       Pm, Ps, Po, out);
}

// Round 5
// 145.436 us; speedup vs baseline: 1.6563x; 1.3850x over previous
//
#include <hip/hip_runtime.h>
#include <hip/hip_bf16.h>

#define N_   4096
#define CIN  256
#define NH_  8
#define DH_  32

typedef __attribute__((ext_vector_type(8))) short bf16x8;
typedef __attribute__((ext_vector_type(4))) float f32x4;

static __device__ inline unsigned short f2bf(float f) {
    union { float f; unsigned u; } x; x.f = f;
    unsigned r = x.u + 0x7FFFu + ((x.u >> 16) & 1u);
    return (unsigned short)(r >> 16);
}
static __device__ inline unsigned cvt_pk_bf16(float a, float b) {
    unsigned r;   // D.lo = bf16(a), D.hi = bf16(b)
    asm("v_cvt_pk_bf16_f32 %0, %1, %2" : "=v"(r) : "v"(a), "v"(b));
    return r;
}

// ---------------- 1) weight norm: W[mat][ch][c] = g[ch]*v[ch][c]/||v[ch,:]|| (bf16) ----
__global__ void wn_kernel(const float* __restrict__ vq, const float* __restrict__ gq,
                          const float* __restrict__ vk, const float* __restrict__ gk,
                          const float* __restrict__ vv, const float* __restrict__ gv,
                          unsigned short* __restrict__ W)
{
    int row = blockIdx.x & 255;
    int mat = blockIdx.x >> 8;
    const float* v = (mat == 0) ? vq : (mat == 1 ? vk : vv);
    const float* g = (mat == 0) ? gq : (mat == 1 ? gk : gv);
    int lane = threadIdx.x;  // 64 threads
    float4 x = *(const float4*)(v + (size_t)row * CIN + lane * 4);
    float ss = x.x*x.x + x.y*x.y + x.z*x.z + x.w*x.w;
    for (int m = 1; m < 64; m <<= 1) ss += __shfl_xor(ss, m);
    float sc = g[row] * rsqrtf(ss);
    unsigned short w4[4] = {f2bf(x.x*sc), f2bf(x.y*sc), f2bf(x.z*sc), f2bf(x.w*sc)};
    *(unsigned long long*)(W + (size_t)mat*65536 + (size_t)row*CIN + lane*4) =
        *(unsigned long long*)w4;
}

// ---------------- 2) projection GEMMs (unchanged from round 4) ----------------------
__global__ __launch_bounds__(256) void proj_kernel(
    const float* __restrict__ query, const float* __restrict__ keyf,
    const unsigned short* __restrict__ W,
    const float* __restrict__ bq, const float* __restrict__ bk, const float* __restrict__ bv,
    unsigned short* __restrict__ Qb, unsigned short* __restrict__ Kb,
    unsigned short* __restrict__ VTb)
{
    __shared__ unsigned short At[16][272];
    int t = threadIdx.x;
    int mat   = blockIdx.x >> 8;
    int ntile = blockIdx.x & 255;
    int nbase = ntile * 16;
    const float* X = (mat == 0) ? query : keyf;
    const unsigned short* Wm = W + (size_t)mat * 65536;
    const float* bias = (mat == 0) ? bq : (mat == 1 ? bk : bv);
    float scale = (mat == 0) ? 0.2550695314903135f : 1.0f;  // log2(e)/sqrt(32) into Q

    int tr = t >> 4;
    int tn = t & 15;
    #pragma unroll
    for (int p = 0; p < 16; ++p) {
        int c = p*16 + tr;
        At[tn][c] = f2bf(X[(size_t)c * N_ + nbase + tn]);
    }
    __syncthreads();

    int w = t >> 6;
    int lane = t & 63;
    int lg = lane >> 4;
    int lr = lane & 15;

    f32x4 acc[4];
    #pragma unroll
    for (int tt = 0; tt < 4; ++tt) acc[tt] = (f32x4){0,0,0,0};

    #pragma unroll
    for (int kk = 0; kk < 8; ++kk) {
        int c0 = kk*32 + lg*8;
        bf16x8 a = *(const bf16x8*)&At[lr][c0];
        #pragma unroll
        for (int tt = 0; tt < 4; ++tt) {
            int ch = w*64 + tt*16 + lr;
            bf16x8 b = *(const bf16x8*)(Wm + (size_t)ch*CIN + c0);
            acc[tt] = __builtin_amdgcn_mfma_f32_16x16x32_bf16(a, b, acc[tt], 0, 0, 0);
        }
    }
    #pragma unroll
    for (int tt = 0; tt < 4; ++tt) {
        int ch = w*64 + tt*16 + lr;
        float bb = bias[ch];
        int head = ch >> 5, d = ch & 31;
        #pragma unroll
        for (int r = 0; r < 4; ++r) {
            int n = nbase + lg*4 + r;
            unsigned short val = f2bf((acc[tt][r] + bb) * scale);
            if (mat == 0)      Qb[((size_t)head*N_ + n)*DH_ + d] = val;
            else if (mat == 1) Kb[((size_t)head*N_ + n)*DH_ + d] = val;
            else               VTb[((size_t)head*DH_ + d)*N_ + n] = val;
        }
    }
}

// ---------------- 3) flash attention: block=(head,qtile), 4 waves split-K ----------
// Swapped QK^T (mfma(K,Q)): lane holds P-row q=lr in regs -> in-lane softmax.
// P->A-frag via per-wave XOR-swizzled LDS tile. No barrier in the loop.
__global__ __launch_bounds__(256, 4) void attn_kernel(
    const unsigned short* __restrict__ Qb, const unsigned short* __restrict__ Kb,
    const unsigned short* __restrict__ VTb, float* __restrict__ out)
{
    __shared__ __attribute__((aligned(16))) unsigned short Plds[4][16][64]; // 8 KB, swizzled
    __shared__ float Ow[4][16][33];   // per-wave O partials (pad 33)
    __shared__ float Mw[4][16];
    __shared__ float Sw[4][16];
    __shared__ float mlds[4][16];     // m broadcast q=lr -> q=lg*4+r (rescale only)

    int tid = threadIdx.x;
    int w    = tid >> 6;
    int lane = tid & 63;
    int lg = lane >> 4, lr = lane & 15;
    int b = blockIdx.x;
    int head  = b & 7;
    int qtile = 255 - (b >> 3);       // largest trip counts first
    int qbase = qtile << 4;

    const unsigned short* Qh = Qb  + (size_t)head * (N_ * DH_);
    const unsigned short* Kh = Kb  + (size_t)head * (N_ * DH_);
    const unsigned short* Vh = VTb + (size_t)head * (DH_ * N_);

    bf16x8 qf = *(const bf16x8*)(Qh + (size_t)(qbase + lr) * DH_ + lg * 8);
    f32x4 zero = {0,0,0,0};
    f32x4 o0 = zero, o1 = zero;       // D: q = lg*4+r, d = lr / 16+lr
    float m = -1e30f, sum = 0.0f;     // state for q = lr (lg-replicated)
    float mB[4] = {-1e30f, -1e30f, -1e30f, -1e30f};  // O-side m, q = lg*4+r

    char* prow = (char*)&Plds[w][lr][0];
    int swz = (lr & 7) << 4;          // XOR-swizzle, 16B granularity (G4 recipe)

    int nblk = (qbase + 15 + 63) >> 6;
    for (int t = w; t < nblk; t += 4) {
        int kb = t << 6;
        // --- S^T = K Q^T : lane holds S[k = kb+jb*16+lg*4+r][q = qbase+lr] ---
        f32x4 s[4];
        #pragma unroll
        for (int jb = 0; jb < 4; ++jb) {
            bf16x8 kf = *(const bf16x8*)(Kh + (size_t)(kb + jb*16 + lr) * DH_ + lg*8);
            s[jb] = __builtin_amdgcn_mfma_f32_16x16x32_bf16(kf, qf, zero, 0, 0, 0);
        }
        if (kb + 63 >= qbase) {       // strict-causal mask on diagonal blocks
            #pragma unroll
            for (int jb = 0; jb < 4; ++jb)
                #pragma unroll
                for (int r = 0; r < 4; ++r)
                    if (kb + jb*16 + lg*4 + r >= qbase + lr) s[jb][r] = -INFINITY;
        }
        // --- in-lane tile max for q = lr, then 2 shuffles across lg ---
        float v = fmaxf(fmaxf(fmaxf(s[0][0],s[0][1]), fmaxf(s[0][2],s[0][3])),
                        fmaxf(fmaxf(s[1][0],s[1][1]), fmaxf(s[1][2],s[1][3])));
        v = fmaxf(v, fmaxf(fmaxf(fmaxf(s[2][0],s[2][1]), fmaxf(s[2][2],s[2][3])),
                           fmaxf(fmaxf(s[3][0],s[3][1]), fmaxf(s[3][2],s[3][3]))));
        v = fmaxf(v, __shfl_xor(v, 16));
        v = fmaxf(v, __shfl_xor(v, 32));
        if (__any((int)(v > m + 8.0f))) {   // defer-max: rare, wave-uniform
            float mn = fmaxf(m, v);
            sum *= exp2f(m - mn);
            m = mn;
            if (lg == 0) mlds[w][lr] = mn;
            #pragma unroll
            for (int r = 0; r < 4; ++r) {
                float nm = mlds[w][lg*4 + r];
                float fr = exp2f(mB[r] - nm);
                o0[r] *= fr;  o1[r] *= fr;
                mB[r] = nm;
            }
        }
        // --- P = exp2(S - m), pack bf16, scatter into swizzled LDS row q=lr ---
        float ps = 0.0f;
        #pragma unroll
        for (int jb = 0; jb < 4; ++jb) {
            float p0 = exp2f(s[jb][0] - m), p1 = exp2f(s[jb][1] - m);
            float p2 = exp2f(s[jb][2] - m), p3 = exp2f(s[jb][3] - m);
            ps += (p0 + p1) + (p2 + p3);
            uint2 pk; pk.x = cvt_pk_bf16(p0, p1); pk.y = cvt_pk_bf16(p2, p3);
            *(uint2*)(prow + ((jb*32 + lg*8) ^ swz)) = pk;
        }
        sum += ps;
        // --- PV: A = P (row q=lr, k=lg*8+j), B = V^T rows (col d, k contiguous) ---
        bf16x8 pa0 = *(const bf16x8*)(prow + ((     lg*16) ^ swz));
        bf16x8 pa1 = *(const bf16x8*)(prow + ((64 + lg*16) ^ swz));
        bf16x8 vb00 = *(const bf16x8*)(Vh + (size_t)lr        * N_ + kb      + lg*8);
        bf16x8 vb01 = *(const bf16x8*)(Vh + (size_t)(16 + lr) * N_ + kb      + lg*8);
        bf16x8 vb10 = *(const bf16x8*)(Vh + (size_t)lr        * N_ + kb + 32 + lg*8);
        bf16x8 vb11 = *(const bf16x8*)(Vh + (size_t)(16 + lr) * N_ + kb + 32 + lg*8);
        o0 = __builtin_amdgcn_mfma_f32_16x16x32_bf16(pa0, vb00, o0, 0, 0, 0);
        o0 = __builtin_amdgcn_mfma_f32_16x16x32_bf16(pa1, vb10, o0, 0, 0, 0);
        o1 = __builtin_amdgcn_mfma_f32_16x16x32_bf16(pa0, vb01, o1, 0, 0, 0);
        o1 = __builtin_amdgcn_mfma_f32_16x16x32_bf16(pa1, vb11, o1, 0, 0, 0);
    }

    // --- per-wave epilogue: total sum for q=lr, stash (m, sum, O) in LDS ---
    sum += __shfl_xor(sum, 16);
    sum += __shfl_xor(sum, 32);
    if (lg == 0) { Mw[w][lr] = m; Sw[w][lr] = sum; }
    #pragma unroll
    for (int r = 0; r < 4; ++r) {
        Ow[w][lg*4 + r][lr]      = o0[r];
        Ow[w][lg*4 + r][16 + lr] = o1[r];
    }
    __syncthreads();

    // --- in-block combine across 4 waves: thread -> (q, d-pair) ---
    int q  = tid & 15;
    int dg = tid >> 4;                 // d = 2*dg, 2*dg+1
    float mw[4], sw[4];
    #pragma unroll
    for (int wv = 0; wv < 4; ++wv) {
        sw[wv] = Sw[wv][q];
        mw[wv] = (sw[wv] > 0.0f) ? Mw[wv][q] : -1e30f;
    }
    float M = fmaxf(fmaxf(mw[0], mw[1]), fmaxf(mw[2], mw[3]));
    float den = 0.0f, a0 = 0.0f, a1 = 0.0f;
    #pragma unroll
    for (int wv = 0; wv < 4; ++wv) {
        float wgt = exp2f(mw[wv] - M);
        den += sw[wv] * wgt;
        a0  += wgt * Ow[wv][q][dg*2];
        a1  += wgt * Ow[wv][q][dg*2 + 1];
    }
    int grow = qbase + q;
    float inv = (grow != 0 && den > 0.0f) ? 1.0f / den : 0.0f;  // row 0: start_mask
    out[(size_t)(head*DH_ + dg*2    ) * N_ + grow] = a0 * inv;
    out[(size_t)(head*DH_ + dg*2 + 1) * N_ + grow] = a1 * inv;
}

extern "C" void kernel_launch(void* const* d_in, const int* in_sizes, int n_in,
                              void* d_out, int out_size, void* d_ws, size_t ws_size,
                              hipStream_t stream) {
    const float* query = (const float*)d_in[0];
    const float* keyf  = (const float*)d_in[1];
    const float* vq = (const float*)d_in[2];
    const float* gq = (const float*)d_in[3];
    const float* bq = (const float*)d_in[4];
    const float* vk = (const float*)d_in[5];
    const float* gk = (const float*)d_in[6];
    const float* bk = (const float*)d_in[7];
    const float* vv = (const float*)d_in[8];
    const float* gv = (const float*)d_in[9];
    const float* bv = (const float*)d_in[10];

    char* ws = (char*)d_ws;
    unsigned short* W   = (unsigned short*)ws;                    // 384 KB
    unsigned short* Qb  = (unsigned short*)(ws + 393216);         // 2 MB
    unsigned short* Kb  = (unsigned short*)(ws + 2490368);        // 2 MB
    unsigned short* VTb = (unsigned short*)(ws + 4587520);        // 2 MB
    float* out = (float*)d_out;

    hipLaunchKernelGGL(wn_kernel,   dim3(768),  dim3(64),  0, stream,
                       vq, gq, vk, gk, vv, gv, W);
    hipLaunchKernelGGL(proj_kernel, dim3(768),  dim3(256), 0, stream,
                       query, keyf, W, bq, bk, bv, Qb, Kb, VTb);
    hipLaunchKernelGGL(attn_kernel, dim3(2048), dim3(256), 0, stream,
                       Qb, Kb, VTb, out);
}